// Round 8
// baseline (563.121 us; speedup 1.0000x reference)
//
#include <hip/hip_runtime.h>
#include <cstdint>
#include <cstddef>

static constexpr int Bb = 8;
static constexpr int Nn = 2048;
static constexpr int Kn = 20;
static constexpr float EPSV = 1e-5f;

// ---------------------------------------------------------------- utilities

// weight transposes in one launch: out[c*R + r] = in[r*Cc + c]
struct TransJobs {
    const float* in[6];
    float* out[6];
    int R[6];
    int Cc[6];
};

__global__ void transpose_all_kernel(TransJobs tj) {
    int m = blockIdx.y;
    int i = blockIdx.x * 256 + threadIdx.x;
    int total = tj.R[m] * tj.Cc[m];
    if (i < total) {
        int r = i / tj.Cc[m], c = i % tj.Cc[m];
        tj.out[m][(size_t)c * tj.R[m] + r] = tj.in[m][i];
    }
}

using half8 = __attribute__((ext_vector_type(8))) _Float16;
using f32x16 = __attribute__((ext_vector_type(16))) float;

// ------------------- layer-1 prep (C=3 only): z-projection + packed xx + zero
// blocks [0,1024): Z1/Z2 projection for a 16-point tile
// blocks [1024,1088): xx[i] + packed (x,xx) float4
// blocks [1088,1216): zero the 32K-float SSUM+SSQ region

template<int C, int O>
__global__ void prep_kernel(const float* __restrict__ x, const float* __restrict__ wt,
                            float* __restrict__ z1, float* __restrict__ z2,
                            float* __restrict__ xx, float4* __restrict__ xp,
                            float* __restrict__ zp) {
    const int blk = blockIdx.x;
    const int tid = threadIdx.x;
    if (blk >= 1088) {
        zp[(blk - 1088) * 256 + tid] = 0.f;
        return;
    }
    if (blk >= 1024) {
        int i = (blk - 1024) * 256 + tid;
        const float* xr = x + (size_t)i * C;
        float s = 0.f;
        for (int c = 0; c < C; ++c) { float v = xr[c]; s += v * v; }
        xx[i] = s;
        if (C == 3) xp[i] = make_float4(xr[0], xr[1], xr[2], s);
        return;
    }
    // z projection (layer 1 path)
    constexpr int TP = 16;
    constexpr int G = 256 / O;
    constexpr int PP = TP / G;
    const int p0 = blk * TP;
    const int oo = tid % O;
    const int g = tid / O;
    __shared__ float xs[TP][(C < 4) ? 4 : C];
    for (int e = tid; e < TP * C; e += 256) {
        int p = e / C, c = e % C;
        xs[p][c] = x[(size_t)(p0 + p) * C + c];
    }
    __syncthreads();
    float a1[PP], a2[PP];
#pragma unroll
    for (int p = 0; p < PP; ++p) { a1[p] = 0.f; a2[p] = 0.f; }
    for (int c = 0; c < C; ++c) {
        float w1 = wt[(size_t)c * O + oo];
        float w2 = wt[(size_t)(C + c) * O + oo];
#pragma unroll
        for (int p = 0; p < PP; ++p) {
            float xv = xs[g * PP + p][c];
            a1[p] = fmaf(xv, w1, a1[p]);
            a2[p] = fmaf(xv, w2, a2[p]);
        }
    }
#pragma unroll
    for (int p = 0; p < PP; ++p) {
        size_t row = (size_t)(p0 + g * PP + p) * O + oo;
        z1[row] = a1[p];
        z2[row] = a2[p];
    }
}

// ------------------- layers 2-4 tiny prep: xx (exact old order) + stat-zero

template<int C>
__global__ void slim2_prep_kernel(const float* __restrict__ x,
                                  float* __restrict__ xx, float* __restrict__ zp) {
    const int blk = blockIdx.x;
    const int tid = threadIdx.x;
    if (blk < 64) {
        int i = blk * 256 + tid;
        const float* xr = x + (size_t)i * C;
        float s = 0.f;
        for (int c = 0; c < C; ++c) { float v = xr[c]; s += v * v; }
        xx[i] = s;
        return;
    }
    zp[(blk - 64) * 256 + tid] = 0.f;
}

// ------------------- z-projection on matrix cores (R16: gram-style clone)
// z1 = x @ W[:, :C]^T, z2 = x @ W[:, C:2C]^T via the verified 2-way fp16
// split (inner = hh + 2^-12*(h*l'+l*h')). Structure cloned from
// gram_dist_kernel: coalesced f32 panel loads -> inline h/l split ->
// rotated-slot LDS staging -> conflict-free ds_read_b128 fragments ->
// 2x2x2 MFMA.

template<int C, int O>
__global__ __launch_bounds__(256, 2)
void zmfma_kernel(const float* __restrict__ x, const float* __restrict__ w,
                  float* __restrict__ z1, float* __restrict__ z2) {
    static_assert(C % 32 == 0 && (2 * O) % 128 == 0 && O >= 64, "tiling");
    constexpr int CT = 32;
    const int i0 = blockIdx.x * 128;           // output rows (points)
    const int j0 = blockIdx.y * 128;           // output cols in [0, 2O)
    const int tid = threadIdx.x;
    const int lane = tid & 63;
    const int wv = tid >> 6;
    const int wr = wv >> 1, wc = wv & 1;

    __shared__ __align__(16) unsigned char smem[32768];
    _Float16* const AH = (_Float16*)smem;      // [4][128][8] halfs, 8 KB each
    _Float16* const AL = AH + 4096;
    _Float16* const BH = AH + 8192;
    _Float16* const BL = AH + 12288;

    int sga[4];
    const float* sgs[4];
#pragma unroll
    for (int q = 0; q < 4; ++q) {
        int g = tid + 256 * q;                 // q<2 -> A panel (x rows), q>=2 -> B panel (W rows)
        int pnt = (g >> 2) & 127;
        int cb8 = g & 3;
        sga[q] = cb8 * 128 + (pnt & ~7) + ((pnt + 2 * cb8) & 7);
        if (q < 2) {
            sgs[q] = x + (size_t)(i0 + pnt) * C + cb8 * 8;
        } else {
            int gcol = j0 + pnt;
            int s = (gcol >= O) ? 1 : 0;
            int o = gcol - s * O;
            sgs[q] = w + (size_t)o * (2 * C) + s * C + cb8 * 8;
        }
    }

    int fa[2][2], fb[2][2];
#pragma unroll
    for (int ks = 0; ks < 2; ++ks)
#pragma unroll
        for (int mi = 0; mi < 2; ++mi) {
            int t8 = ks * 2 + (lane >> 5);
            int pa = wr * 64 + mi * 32 + (lane & 31);
            int pb = wc * 64 + mi * 32 + (lane & 31);
            fa[ks][mi] = t8 * 128 + (pa & ~7) + ((pa + 2 * t8) & 7);
            fb[ks][mi] = t8 * 128 + (pb & ~7) + ((pb + 2 * t8) & 7);
        }

    f32x16 ahh[2][2] = {};   // SUM h*h'
    f32x16 axx[2][2] = {};   // SUM h*l' + l*h'   (carries the 4096 scale)

    for (int c0 = 0; c0 < C; c0 += CT) {
#pragma unroll
        for (int q = 0; q < 4; ++q) {
            const float4 f0 = *(const float4*)(sgs[q] + c0);
            const float4 f1 = *(const float4*)(sgs[q] + c0 + 4);
            float v[8] = {f0.x, f0.y, f0.z, f0.w, f1.x, f1.y, f1.z, f1.w};
            half8 hv, lv;
#pragma unroll
            for (int e = 0; e < 8; ++e) {
                _Float16 h = (_Float16)v[e];
                hv[e] = h;
                lv[e] = (_Float16)((v[e] - (float)h) * 4096.f);
            }
            _Float16* dh = (q < 2) ? AH : BH;
            _Float16* dl = (q < 2) ? AL : BL;
            *(half8*)(dh + sga[q] * 8) = hv;
            *(half8*)(dl + sga[q] * 8) = lv;
        }
        __syncthreads();
#pragma unroll
        for (int ks = 0; ks < 2; ++ks) {
            half8 ah[2], al[2], bh[2], bl[2];
#pragma unroll
            for (int mi = 0; mi < 2; ++mi) {
                ah[mi] = *(const half8*)(AH + fa[ks][mi] * 8);
                al[mi] = *(const half8*)(AL + fa[ks][mi] * 8);
                bh[mi] = *(const half8*)(BH + fb[ks][mi] * 8);
                bl[mi] = *(const half8*)(BL + fb[ks][mi] * 8);
            }
#pragma unroll
            for (int mi = 0; mi < 2; ++mi)
#pragma unroll
                for (int ni = 0; ni < 2; ++ni) {
                    ahh[mi][ni] = __builtin_amdgcn_mfma_f32_32x32x16_f16(ah[mi], bh[ni], ahh[mi][ni], 0, 0, 0);
                    axx[mi][ni] = __builtin_amdgcn_mfma_f32_32x32x16_f16(ah[mi], bl[ni], axx[mi][ni], 0, 0, 0);
                    axx[mi][ni] = __builtin_amdgcn_mfma_f32_32x32x16_f16(al[mi], bh[ni], axx[mi][ni], 0, 0, 0);
                }
        }
        __syncthreads();
    }

    // epilogue: z = hh + 2^-12 * cross; per-(wc,ni) wave-uniform z1/z2 select.
    // C/D layout: col = lane&31, row = (r&3) + 8*(r>>2) + 4*(lane>>5).
#pragma unroll
    for (int mi = 0; mi < 2; ++mi)
#pragma unroll
        for (int ni = 0; ni < 2; ++ni) {
            const int cb = wc * 64 + ni * 32;
            const int s = ((j0 + cb) >= O) ? 1 : 0;
            float* outp = s ? z2 : z1;
            const int o = j0 + cb - s * O + (lane & 31);
#pragma unroll
            for (int r = 0; r < 16; ++r) {
                int row = i0 + wr * 64 + mi * 32 + (r & 3) + 8 * (r >> 2) + 4 * (lane >> 5);
                outp[(size_t)row * O + o] = fmaf(axx[mi][ni][r], 2.44140625e-4f, ahh[mi][ni][r]);
            }
        }
}

// ------------------------------------------------ pairwise sq-dist (tiled gram)
// SYMMETRIC: only the 136 upper-triangular 128x128 block-pairs are computed;
// off-diagonal blocks emit the mirrored tile through a FULL 128x132 LDS
// transpose buffer (R17): ONE barrier + one coalesced copy-out, instead of
// 4 chunks x 2 barriers. Every __syncthreads drains vmcnt(0) (compiler
// emits a full waitcnt before s_barrier), so the old 8-barrier mirror
// force-drained the store stream 8x per block -> gram was wait-bound at
// 54 us (MfmaUtil 9%, HBM 39%). Staging smem (32 KB) is dead by mirror
// time; the 67.6 KB T2 aliases it. 2 blocks/CU unchanged (135 KB < 160 KB).
// R10: matrix-core inner products via 2-way fp16 split.
// R11 (rule #20): accumulator subscripts must be compile-time — runtime
// indexing sent f32x16 accs to SCRATCH (1.27 GB HBM traffic, 276 us).

template<int C>
__global__ __launch_bounds__(256, 2)
void gram_dist_kernel(const float* __restrict__ x, const float* __restrict__ xx,
                      float* __restrict__ dist, int b0, size_t dstride) {
    static_assert(C % 32 == 0, "CT=32 tiling");
    constexpr int CT = 32;
    const int b = b0 + blockIdx.z;
    // decode upper-tri pair index -> (rblk, cblk), rblk <= cblk, 16x16 tiles
    int p = blockIdx.x, rblk = 0;
    while (p >= 16 - rblk) { p -= 16 - rblk; ++rblk; }
    const int cblk = rblk + p;
    const int i0 = rblk * 128, j0 = cblk * 128;
    const int tid = threadIdx.x;
    const int lane = tid & 63;
    const int wv = tid >> 6;
    const int wr = wv >> 1, wc = wv & 1;   // wave quadrant: rows wr*64.., cols wc*64..

    __shared__ __align__(16) unsigned char smem[67584];   // max(staging 32KB, T2 128*132*4)
    _Float16* const AH = (_Float16*)smem;          // [4][128][8] halfs, 8 KB
    _Float16* const AL = AH + 4096;
    _Float16* const BH = AH + 8192;
    _Float16* const BL = AH + 12288;
    float (*T2)[132] = (float (*)[132])smem;       // full mirror buffer, post-loop alias

    const float* xb = x + (size_t)b * Nn * C;
    int sga[4];
    const float* sgs[4];
#pragma unroll
    for (int q = 0; q < 4; ++q) {
        int g = tid + 256 * q;                 // q<2 -> A panel (i0), q>=2 -> B panel (j0)
        int pnt = (g >> 2) & 127;
        int cb8 = g & 3;
        sga[q] = cb8 * 128 + (pnt & ~7) + ((pnt + 2 * cb8) & 7);
        sgs[q] = xb + (size_t)(((q < 2) ? i0 : j0) + pnt) * C + cb8 * 8;
    }

    int fa[2][2], fb[2][2];
#pragma unroll
    for (int ks = 0; ks < 2; ++ks)
#pragma unroll
        for (int mi = 0; mi < 2; ++mi) {
            int t8 = ks * 2 + (lane >> 5);
            int pa = wr * 64 + mi * 32 + (lane & 31);
            int pb = wc * 64 + mi * 32 + (lane & 31);
            fa[ks][mi] = t8 * 128 + (pa & ~7) + ((pa + 2 * t8) & 7);
            fb[ks][mi] = t8 * 128 + (pb & ~7) + ((pb + 2 * t8) & 7);
        }

    f32x16 ahh[2][2] = {};   // SUM h*h'
    f32x16 axx[2][2] = {};   // SUM h*l' + l*h'   (carries the 4096 scale)

    for (int c0 = 0; c0 < C; c0 += CT) {
#pragma unroll
        for (int q = 0; q < 4; ++q) {
            const float4 f0 = *(const float4*)(sgs[q] + c0);
            const float4 f1 = *(const float4*)(sgs[q] + c0 + 4);
            float v[8] = {f0.x, f0.y, f0.z, f0.w, f1.x, f1.y, f1.z, f1.w};
            half8 hv, lv;
#pragma unroll
            for (int e = 0; e < 8; ++e) {
                _Float16 h = (_Float16)v[e];
                hv[e] = h;
                lv[e] = (_Float16)((v[e] - (float)h) * 4096.f);
            }
            _Float16* dh = (q < 2) ? AH : BH;
            _Float16* dl = (q < 2) ? AL : BL;
            *(half8*)(dh + sga[q] * 8) = hv;
            *(half8*)(dl + sga[q] * 8) = lv;
        }
        __syncthreads();
#pragma unroll
        for (int ks = 0; ks < 2; ++ks) {
            half8 ah[2], al[2], bh[2], bl[2];
#pragma unroll
            for (int mi = 0; mi < 2; ++mi) {
                ah[mi] = *(const half8*)(AH + fa[ks][mi] * 8);
                al[mi] = *(const half8*)(AL + fa[ks][mi] * 8);
                bh[mi] = *(const half8*)(BH + fb[ks][mi] * 8);
                bl[mi] = *(const half8*)(BL + fb[ks][mi] * 8);
            }
#pragma unroll
            for (int mi = 0; mi < 2; ++mi)
#pragma unroll
                for (int ni = 0; ni < 2; ++ni) {
                    ahh[mi][ni] = __builtin_amdgcn_mfma_f32_32x32x16_f16(ah[mi], bh[ni], ahh[mi][ni], 0, 0, 0);
                    axx[mi][ni] = __builtin_amdgcn_mfma_f32_32x32x16_f16(ah[mi], bl[ni], axx[mi][ni], 0, 0, 0);
                    axx[mi][ni] = __builtin_amdgcn_mfma_f32_32x32x16_f16(al[mi], bh[ni], axx[mi][ni], 0, 0, 0);
                }
        }
        __syncthreads();
    }

    // epilogue: dist = xx_i + xx_j - 2*(hh + 2^-12 * cross)
    const float* xxb = xx + (size_t)b * Nn;
    float xi[2][16];
#pragma unroll
    for (int mi = 0; mi < 2; ++mi)
#pragma unroll
        for (int g = 0; g < 4; ++g) {
            float4 t4 = *(const float4*)(xxb + i0 + wr * 64 + mi * 32 + 4 * (lane >> 5) + 8 * g);
            xi[mi][g * 4 + 0] = t4.x; xi[mi][g * 4 + 1] = t4.y;
            xi[mi][g * 4 + 2] = t4.z; xi[mi][g * 4 + 3] = t4.w;
        }
    float xj[2];
#pragma unroll
    for (int ni = 0; ni < 2; ++ni) xj[ni] = xxb[j0 + wc * 64 + ni * 32 + (lane & 31)];

    float* db = dist + (size_t)blockIdx.z * dstride;
#pragma unroll
    for (int mi = 0; mi < 2; ++mi)
#pragma unroll
        for (int ni = 0; ni < 2; ++ni) {
            const int col = j0 + wc * 64 + ni * 32 + (lane & 31);
#pragma unroll
            for (int r = 0; r < 16; ++r) {
                int row = i0 + wr * 64 + mi * 32 + (r & 3) + 8 * (r >> 2) + 4 * (lane >> 5);
                float inner = fmaf(axx[mi][ni][r], 2.44140625e-4f, ahh[mi][ni][r]);
                db[(size_t)row * Nn + col] = xi[mi][r] + xj[ni] - 2.f * inner;
            }
        }

    if (cblk > rblk) {
        // mirror tile (j0.., i0..): every wave writes its full quadrants into
        // T2 (bitwise-identical expression), ONE barrier, coalesced copy-out.
        // All subscripts compile-time (rule #20).
#pragma unroll
        for (int mi = 0; mi < 2; ++mi)
#pragma unroll
            for (int ni = 0; ni < 2; ++ni) {
                const int mrow = wc * 64 + ni * 32 + (lane & 31);   // mirror row (orig col)
#pragma unroll
                for (int r = 0; r < 16; ++r) {
                    int mcol = wr * 64 + mi * 32 + (r & 3) + 8 * (r >> 2) + 4 * (lane >> 5);
                    float inner = fmaf(axx[mi][ni][r], 2.44140625e-4f, ahh[mi][ni][r]);
                    T2[mrow][mcol] = xi[mi][r] + xj[ni] - 2.f * inner;
                }
            }
        __syncthreads();
        const int rr = tid >> 3;            // 0..31 row within 32-row group
        const int c4 = (tid & 7) * 4;       // col base (float4 granularity)
#pragma unroll
        for (int m = 0; m < 4; ++m) {
            const int row = m * 32 + rr;
            float* orow = db + (size_t)(j0 + row) * Nn + i0;
#pragma unroll
            for (int s = 0; s < 4; ++s)
                *(float4*)(orow + c4 + s * 32) = *(const float4*)&T2[row][c4 + s * 32];
        }
    }
}

// ------------------------------------------------------- top-k (k=20 smallest)
// R14: PACKED-KEY selection. In-lane candidate ordinal m (5 bits) is packed
// into the 5 low mantissa bits: key = (bits(v) & ~31) | m. In-lane keys are
// distinct -> strict-< ladder exact; winner decode free (m from key bits,
// lane from ballot); no tie-butterfly; rebuild filter = single compare.
// Ranking perturbation 2^-19 rel ~ same class as fp16-split dist error.

template<int CTRL>
__device__ __forceinline__ float dpp_min_step(float v) {
    int x = __float_as_int(v);
    int y = __builtin_amdgcn_update_dpp(x, x, CTRL, 0xf, 0xf, false);
    return fminf(v, __int_as_float(y));
}

// full-wave (64-lane) min; returns the min broadcast to all lanes (SGPR).
__device__ __forceinline__ float wave_min64(float v) {
    v = dpp_min_step<0x111>(v);   // row_shr:1
    v = dpp_min_step<0x112>(v);   // row_shr:2
    v = dpp_min_step<0x114>(v);   // row_shr:4
    v = dpp_min_step<0x118>(v);   // row_shr:8
    v = dpp_min_step<0x142>(v);   // row_bcast:15
    v = dpp_min_step<0x143>(v);   // row_bcast:31
    return __int_as_float(__builtin_amdgcn_readlane(__float_as_int(v), 63));
}

__device__ __forceinline__ float pack_key(float v, int m) {
    return __int_as_float((__float_as_int(v) & ~31) | m);
}

#define TOP4_INS(v)                                                               \
    {                                                                             \
        bool l3 = (v) < tv3;                                                      \
        if (l3) {                                                                 \
            bool l2 = (v) < tv2;                                                  \
            bool l1 = (v) < tv1;                                                  \
            bool l0 = (v) < tv0;                                                  \
            tv3 = l2 ? tv2 : (v);                                                 \
            tv2 = l2 ? (l1 ? tv1 : (v)) : tv2;                                    \
            tv1 = l1 ? (l0 ? tv0 : (v)) : tv1;                                    \
            tv0 = l0 ? (v) : tv0;                                                 \
        }                                                                         \
    }

__device__ __forceinline__ void top4_build(const float4* __restrict__ dr4, int lane,
                                           float lvk,
                                           float& tv0, float& tv1, float& tv2, float& tv3) {
    tv0 = tv1 = tv2 = tv3 = 3e38f;
#pragma unroll
    for (int q = 0; q < 8; ++q) {
        float4 f = dr4[q * 64 + lane];
        float vv[4] = {f.x, f.y, f.z, f.w};
#pragma unroll
        for (int c = 0; c < 4; ++c) {
            float vk = pack_key(vv[c], q * 4 + c);
            if (vk > lvk) TOP4_INS(vk)
        }
    }
}

#define TOPK_ROUNDS(REBUILD, DECODE)                                              \
    int myj = 0;                                                                  \
    for (int t = 0; t < Kn; ++t) {                                                \
        float bv = wave_min64(tv0);                                               \
        unsigned long long tied = __ballot(tv0 == bv);                            \
        int wl = (int)(__ffsll((long long)tied) - 1);                             \
        int bm = __float_as_int(bv) & 31;                                         \
        int bj = (DECODE);                                                        \
        if (lane == t) myj = bj;                                                  \
        if (tv0 == bv && lane == wl) {                                            \
            tv0 = tv1; tv1 = tv2; tv2 = tv3; tv3 = 3e38f;                         \
            if (tv0 == 3e38f) { REBUILD; }                                        \
        }                                                                         \
    }                                                                             \
    if (lane < Kn) orow[lane] = myj;

__global__ void topk_kernel(const float* __restrict__ dist, int* __restrict__ idxo,
                            int b0, size_t dstride, int rows_per_batch_only) {
    const int w = threadIdx.x >> 6;
    const int lane = threadIdx.x & 63;
    const int lin = blockIdx.x * 4 + w;
    int bz, i;
    if (rows_per_batch_only) { bz = 0; i = lin; }
    else { bz = lin >> 11; i = lin & (Nn - 1); }
    const int b = b0 + bz;
    const float4* dr4 = (const float4*)(dist + (size_t)bz * dstride + (size_t)i * Nn);

    float tv0, tv1, tv2, tv3;
    top4_build(dr4, lane, -3e38f, tv0, tv1, tv2, tv3);

    int* orow = idxo + ((size_t)b * Nn + i) * Kn;
    // j = (q*64+lane)*4 + c, m = q*4+c  ->  j = (m>>2)*256 + lane*4 + (m&3)
    TOPK_ROUNDS(top4_build(dr4, lane, bv, tv0, tv1, tv2, tv3),
                (bm >> 2) * 256 + wl * 4 + (bm & 3))
}

// -------- layer-1 fused top-k: dist computed inline from packed (x,xx) float4.

__device__ __forceinline__ void top4_build_c3(const float4* __restrict__ xpb,
                                              float xi0, float xi1, float xi2, float xxi,
                                              int lane, float lvk,
                                              float& tv0, float& tv1, float& tv2, float& tv3) {
    tv0 = tv1 = tv2 = tv3 = 3e38f;
#pragma unroll
    for (int m = 0; m < 32; ++m) {
        float4 f = xpb[m * 64 + lane];
        float acc = 0.f;
        acc = fmaf(xi0, f.x, acc);
        acc = fmaf(xi1, f.y, acc);
        acc = fmaf(xi2, f.z, acc);
        float v = xxi + f.w - 2.f * acc;
        float vk = pack_key(v, m);
        if (vk > lvk) TOP4_INS(vk)
    }
}

__global__ void topk_c3_kernel(const float4* __restrict__ xp, int* __restrict__ idxo,
                               int b0, int rows_per_batch_only) {
    const int w = threadIdx.x >> 6;
    const int lane = threadIdx.x & 63;
    const int lin = blockIdx.x * 4 + w;
    int bz, i;
    if (rows_per_batch_only) { bz = 0; i = lin; }
    else { bz = lin >> 11; i = lin & (Nn - 1); }
    const int b = b0 + bz;
    const float4* xpb = xp + (size_t)b * Nn;
    const float4 fi = xpb[i];
    const float xi0 = fi.x, xi1 = fi.y, xi2 = fi.z, xxi = fi.w;

    float tv0, tv1, tv2, tv3;
    top4_build_c3(xpb, xi0, xi1, xi2, xxi, lane, -3e38f, tv0, tv1, tv2, tv3);

    int* orow = idxo + ((size_t)b * Nn + i) * Kn;
    // j = m*64 + lane
    TOPK_ROUNDS(top4_build_c3(xpb, xi0, xi1, xi2, xxi, lane, bv, tv0, tv1, tv2, tv3),
                bm * 64 + wl)
}

// -------------------- gather edges, max/min over k + BN partial sums

template<int O>
__global__ void edge_stats_kernel(const float* __restrict__ z1, const float* __restrict__ z2,
                                  const int* __restrict__ idx,
                                  float* __restrict__ vmax, float* __restrict__ vmin,
                                  float* __restrict__ ssum, float* __restrict__ ssq) {
    constexpr int TPP = O / 4;           // threads per point
    constexpr int PPB = 256 / TPP;       // points per block
    const int p0 = blockIdx.x * PPB;
    const int tid = threadIdx.x;
    const int q = tid % TPP;
    const int p = tid / TPP;
    const int oo = q * 4;
    __shared__ int jl[PPB][Kn];
    for (int e = tid; e < PPB * Kn; e += 256)
        jl[e / Kn][e % Kn] = idx[(size_t)(p0 + e / Kn) * Kn + (e % Kn)];
    __syncthreads();
    const int bi = p0 + p;
    const int b = bi >> 11;
    const float4 zi1 = *(const float4*)(z1 + (size_t)bi * O + oo);
    const float4 zi2 = *(const float4*)(z2 + (size_t)bi * O + oo);
    float ax = zi2.x - zi1.x, ay = zi2.y - zi1.y, az = zi2.z - zi1.z, aw = zi2.w - zi1.w;
    float mxx = -3e38f, mxy = -3e38f, mxz = -3e38f, mxw = -3e38f;
    float mnx = 3e38f, mny = 3e38f, mnz = 3e38f, mnw = 3e38f;
    float sx = 0.f, sy = 0.f, sz = 0.f, sw = 0.f;
    float qx = 0.f, qy = 0.f, qz = 0.f, qw = 0.f;
    const float* zbase = z1 + ((size_t)b * Nn) * O + oo;
#pragma unroll
    for (int kk = 0; kk < Kn; ++kk) {
        int j = jl[p][kk];
        float4 v = *(const float4*)(zbase + (size_t)j * O);
        v.x += ax; v.y += ay; v.z += az; v.w += aw;
        mxx = fmaxf(mxx, v.x); mxy = fmaxf(mxy, v.y); mxz = fmaxf(mxz, v.z); mxw = fmaxf(mxw, v.w);
        mnx = fminf(mnx, v.x); mny = fminf(mny, v.y); mnz = fminf(mnz, v.z); mnw = fminf(mnw, v.w);
        sx += v.x; sy += v.y; sz += v.z; sw += v.w;
        qx = fmaf(v.x, v.x, qx); qy = fmaf(v.y, v.y, qy);
        qz = fmaf(v.z, v.z, qz); qw = fmaf(v.w, v.w, qw);
    }
    float4 mx4 = make_float4(mxx, mxy, mxz, mxw);
    float4 mn4 = make_float4(mnx, mny, mnz, mnw);
    *(float4*)(vmax + (size_t)bi * O + oo) = mx4;
    *(float4*)(vmin + (size_t)bi * O + oo) = mn4;
    __shared__ float4 ssm[256], sqq[256];
    ssm[tid] = make_float4(sx, sy, sz, sw);
    sqq[tid] = make_float4(qx, qy, qz, qw);
    __syncthreads();
    if (p == 0) {
#pragma unroll 4
        for (int pp = 1; pp < PPB; ++pp) {
            float4 s4 = ssm[pp * TPP + q];
            float4 q4 = sqq[pp * TPP + q];
            sx += s4.x; sy += s4.y; sz += s4.z; sw += s4.w;
            qx += q4.x; qy += q4.y; qz += q4.z; qw += q4.w;
        }
        int slot = blockIdx.x & 63;
        atomicAdd(&ssum[slot * O + oo + 0], sx);
        atomicAdd(&ssum[slot * O + oo + 1], sy);
        atomicAdd(&ssum[slot * O + oo + 2], sz);
        atomicAdd(&ssum[slot * O + oo + 3], sw);
        atomicAdd(&ssq[slot * O + oo + 0], qx);
        atomicAdd(&ssq[slot * O + oo + 1], qy);
        atomicAdd(&ssq[slot * O + oo + 2], qz);
        atomicAdd(&ssq[slot * O + oo + 3], qw);
    }
}

// ---------------- BN finalize (in-block) + apply + relu + pooling partials

template<int O>
__global__ void apply_pool_kernel(const float* __restrict__ vmax, const float* __restrict__ vmin,
                                  const float* __restrict__ ssum, const float* __restrict__ ssq,
                                  const float* __restrict__ gamma, const float* __restrict__ beta,
                                  float* __restrict__ xout,
                                  float* __restrict__ pmax, float* __restrict__ psum, int obase) {
    constexpr int TPP = O / 4;
    constexpr int PP2 = 256 / TPP;      // points concurrent
    constexpr int S = 128 / PP2;        // iterations
    const int chunk = blockIdx.x;
    const int b = blockIdx.y;
    const int tid = threadIdx.x;
    const int q = tid % TPP;
    const int g = tid / TPP;
    const int oo = q * 4;
    __shared__ __align__(16) float lsc[O], lsh[O];
    for (int o = tid; o < O; o += 256) {
        float s = 0.f, qq = 0.f;
        for (int sl = 0; sl < 64; ++sl) { s += ssum[sl * O + o]; qq += ssq[sl * O + o]; }
        const float cnt = (float)Bb * (float)Nn * (float)Kn;
        float mu = s / cnt;
        float var = qq / cnt - mu * mu;
        float sc_ = gamma[o] / sqrtf(var + EPSV);
        lsc[o] = sc_;
        lsh[o] = beta[o] - mu * sc_;
    }
    __syncthreads();
    const float4 sc = *(const float4*)(lsc + oo);
    const float4 sh = *(const float4*)(lsh + oo);
    float pmx = -3e38f, pmy = -3e38f, pmz = -3e38f, pmw = -3e38f;
    float psx = 0.f, psy = 0.f, psz = 0.f, psw = 0.f;
    const int n0 = chunk * 128;
    for (int s = 0; s < S; ++s) {
        int n = n0 + g + s * PP2;
        size_t ix = ((size_t)b * Nn + n) * O + oo;
        float4 vx = *(const float4*)(vmax + ix);
        float4 vn = *(const float4*)(vmin + ix);
        float4 r;
        r.x = fmaxf(fmaf(sc.x >= 0.f ? vx.x : vn.x, sc.x, sh.x), 0.f);
        r.y = fmaxf(fmaf(sc.y >= 0.f ? vx.y : vn.y, sc.y, sh.y), 0.f);
        r.z = fmaxf(fmaf(sc.z >= 0.f ? vx.z : vn.z, sc.z, sh.z), 0.f);
        r.w = fmaxf(fmaf(sc.w >= 0.f ? vx.w : vn.w, sc.w, sh.w), 0.f);
        *(float4*)(xout + ix) = r;
        pmx = fmaxf(pmx, r.x); pmy = fmaxf(pmy, r.y);
        pmz = fmaxf(pmz, r.z); pmw = fmaxf(pmw, r.w);
        psx += r.x; psy += r.y; psz += r.z; psw += r.w;
    }
    __shared__ float4 sm[256], ss2[256];
    sm[tid] = make_float4(pmx, pmy, pmz, pmw);
    ss2[tid] = make_float4(psx, psy, psz, psw);
    __syncthreads();
    if (g == 0) {
#pragma unroll 4
        for (int gg = 1; gg < PP2; ++gg) {
            float4 m4 = sm[gg * TPP + q];
            float4 s4 = ss2[gg * TPP + q];
            pmx = fmaxf(pmx, m4.x); pmy = fmaxf(pmy, m4.y);
            pmz = fmaxf(pmz, m4.z); pmw = fmaxf(pmw, m4.w);
            psx += s4.x; psy += s4.y; psz += s4.z; psw += s4.w;
        }
        size_t pb = ((size_t)b * 16 + chunk) * 512 + obase + oo;
        *(float4*)(pmax + pb) = make_float4(pmx, pmy, pmz, pmw);
        *(float4*)(psum + pb) = make_float4(psx, psy, psz, psw);
    }
}

// ------------------------------------------- MLP head, K-parallel (R12)

__global__ void head1_kernel(const float* __restrict__ pmax, const float* __restrict__ psum,
                             const float* __restrict__ fct1, float* __restrict__ hp1) {
    const int ks = blockIdx.x;          // 0..15 -> input channels [ks*64, ks*64+64)
    const int b = blockIdx.y;
    const int tid = threadIdx.x;
    __shared__ float gxs[64];
    if (tid < 64) {
        int c = ks * 64 + tid;
        if (c < 512) {
            float mx = -3e38f;
            for (int ch = 0; ch < 16; ++ch)
                mx = fmaxf(mx, pmax[((size_t)b * 16 + ch) * 512 + c]);
            gxs[tid] = mx;
        } else {
            int e = c - 512;
            float s = 0.f;
            for (int ch = 0; ch < 16; ++ch)
                s += psum[((size_t)b * 16 + ch) * 512 + e];
            gxs[tid] = s * (1.f / (float)Nn);
        }
    }
    __syncthreads();
    float h0 = 0.f, h1 = 0.f;
    const float* w = fct1 + (size_t)(ks * 64) * 512;
    for (int c = 0; c < 64; ++c) {
        float gc = gxs[c];
        h0 = fmaf(gc, w[(size_t)c * 512 + tid], h0);
        h1 = fmaf(gc, w[(size_t)c * 512 + tid + 256], h1);
    }
    hp1[((size_t)b * 16 + ks) * 512 + tid] = h0;
    hp1[((size_t)b * 16 + ks) * 512 + tid + 256] = h1;
}

__global__ void head2_kernel(const float* __restrict__ hp1, const float* __restrict__ fc1b,
                             const float* __restrict__ ln1g, const float* __restrict__ ln1b,
                             float* __restrict__ hh) {
    const int b = blockIdx.x;
    const int tid = threadIdx.x;
    __shared__ float red[256];
    float h0 = fc1b[tid], h1 = fc1b[tid + 256];
    for (int ks = 0; ks < 16; ++ks) {
        h0 += hp1[((size_t)b * 16 + ks) * 512 + tid];
        h1 += hp1[((size_t)b * 16 + ks) * 512 + tid + 256];
    }
    red[tid] = h0 + h1;
    __syncthreads();
    for (int st = 128; st > 0; st >>= 1) { if (tid < st) red[tid] += red[tid + st]; __syncthreads(); }
    float mu = red[0] * (1.f / 512.f);
    __syncthreads();
    float d0 = h0 - mu, d1 = h1 - mu;
    red[tid] = d0 * d0 + d1 * d1;
    __syncthreads();
    for (int st = 128; st > 0; st >>= 1) { if (tid < st) red[tid] += red[tid + st]; __syncthreads(); }
    float rs = 1.f / sqrtf(red[0] * (1.f / 512.f) + EPSV);
    hh[(size_t)b * 512 + tid]       = fmaxf(d0 * rs * ln1g[tid] + ln1b[tid], 0.f);
    hh[(size_t)b * 512 + tid + 256] = fmaxf(d1 * rs * ln1g[tid + 256] + ln1b[tid + 256], 0.f);
}

__global__ void head3_kernel(const float* __restrict__ hh, const float* __restrict__ fct2,
                             float* __restrict__ hp2) {
    const int ks = blockIdx.x;          // 0..3 -> hh channels [ks*128, ks*128+128)
    const int b = blockIdx.y;
    const int tid = threadIdx.x;
    __shared__ float hs[128];
    if (tid < 128) hs[tid] = hh[(size_t)b * 512 + ks * 128 + tid];
    __syncthreads();
    float z = 0.f;
    const float* w = fct2 + (size_t)(ks * 128) * 256;
    for (int c = 0; c < 128; ++c)
        z = fmaf(hs[c], w[(size_t)c * 256 + tid], z);
    hp2[((size_t)b * 4 + ks) * 256 + tid] = z;
}

__global__ void head4_kernel(const float* __restrict__ hp2, const float* __restrict__ fc2b,
                             const float* __restrict__ ln2g, const float* __restrict__ ln2b,
                             float* __restrict__ out) {
    const int b = blockIdx.x;
    const int tid = threadIdx.x;
    __shared__ float red[256];
    float z = fc2b[tid];
    for (int ks = 0; ks < 4; ++ks) z += hp2[((size_t)b * 4 + ks) * 256 + tid];
    red[tid] = z;
    __syncthreads();
    for (int st = 128; st > 0; st >>= 1) { if (tid < st) red[tid] += red[tid + st]; __syncthreads(); }
    float mu2 = red[0] * (1.f / 256.f);
    __syncthreads();
    float dz = z - mu2;
    red[tid] = dz * dz;
    __syncthreads();
    for (int st = 128; st > 0; st >>= 1) { if (tid < st) red[tid] += red[tid + st]; __syncthreads(); }
    float rs2 = 1.f / sqrtf(red[0] * (1.f / 256.f) + EPSV);
    out[b * 256 + tid] = dz * rs2 * ln2g[tid] + ln2b[tid];
}

// --------------------------------------------------------------- layer driver

template<int C, int O>
static void run_layer(const float* x, const float* W, const float* gamma, const float* beta,
                      float* xout, float* DIST, float* XX, float4* XP, int* IDX,
                      float* Z1, float* Z2,
                      float* VMX, float* VMN, float* SSUM, float* SSQ,
                      const float* WT, float* PMAX, float* PSUM, int obase, bool big,
                      hipStream_t stream) {
    if constexpr (C == 3) {
        prep_kernel<C, O><<<1216, 256, 0, stream>>>(x, WT, Z1, Z2, XX, XP, SSUM);
        // layer 1: packed (x,xx) is L1-resident -> fused inline-dist top-k.
        if (big) {
            topk_c3_kernel<<<Bb * Nn / 4, 256, 0, stream>>>(XP, IDX, 0, 0);
        } else {
            for (int b = 0; b < Bb; ++b)
                topk_c3_kernel<<<Nn / 4, 256, 0, stream>>>(XP, IDX, b, 1);
        }
    } else {
        // R16: tiny prep (xx + stat-zero) + gram-style MFMA z-projection.
        slim2_prep_kernel<C><<<192, 256, 0, stream>>>(x, XX, SSUM);
        zmfma_kernel<C, O><<<dim3(Bb * Nn / 128, 2 * O / 128), 256, 0, stream>>>(x, W, Z1, Z2);
        if (big) {
            gram_dist_kernel<C><<<dim3(136, 1, Bb), 256, 0, stream>>>(x, XX, DIST, 0, (size_t)Nn * Nn);
            topk_kernel<<<Bb * Nn / 4, 256, 0, stream>>>(DIST, IDX, 0, (size_t)Nn * Nn, 0);
        } else {
            for (int b = 0; b < Bb; ++b) {
                gram_dist_kernel<C><<<dim3(136, 1, 1), 256, 0, stream>>>(x, XX, DIST, b, 0);
                topk_kernel<<<Nn / 4, 256, 0, stream>>>(DIST, IDX, b, 0, 1);
            }
        }
    }
    edge_stats_kernel<O><<<Bb * Nn / (1024 / O), 256, 0, stream>>>(Z1, Z2, IDX, VMX, VMN, SSUM, SSQ);
    apply_pool_kernel<O><<<dim3(16, 8), 256, 0, stream>>>(VMX, VMN, SSUM, SSQ, gamma, beta,
                                                          xout, PMAX, PSUM, obase);
}

extern "C" void kernel_launch(void* const* d_in, const int* in_sizes, int n_in,
                              void* d_out, int out_size, void* d_ws, size_t ws_size,
                              hipStream_t stream) {
    const float* points = (const float*)d_in[0];
    const float* W1 = (const float*)d_in[1];
    const float* g1 = (const float*)d_in[2];
    const float* b1 = (const float*)d_in[3];
    const float* W2 = (const float*)d_in[4];
    const float* g2 = (const float*)d_in[5];
    const float* b2 = (const float*)d_in[6];
    const float* W3 = (const float*)d_in[7];
    const float* g3 = (const float*)d_in[8];
    const float* b3 = (const float*)d_in[9];
    const float* W4 = (const float*)d_in[10];
    const float* g4 = (const float*)d_in[11];
    const float* b4 = (const float*)d_in[12];
    const float* fc1_w = (const float*)d_in[13];
    const float* fc1_b = (const float*)d_in[14];
    const float* ln1g = (const float*)d_in[15];
    const float* ln1b = (const float*)d_in[16];
    const float* fc2_w = (const float*)d_in[17];
    const float* fc2_b = (const float*)d_in[18];
    const float* ln2g = (const float*)d_in[19];
    const float* ln2b = (const float*)d_in[20];

    float* ws = (float*)d_ws;
    const size_t BN = (size_t)Bb * Nn;
    const bool big = ws_size >= (size_t)59826688 * 4;

    size_t off = 0;
    auto take = [&](size_t n) { size_t o = off; off += n; return o; };
    float* DIST = ws + take(big ? (size_t)Bb * Nn * Nn : (size_t)Nn * Nn);
    float* XX   = ws + take(BN);
    float4* XP  = (float4*)(ws + take(BN * 4));
    int*   IDX  = (int*)(ws + take(BN * Kn));
    float* Z1   = ws + take(BN * 256);
    float* Z2   = ws + take(BN * 256);
    float* VMX  = ws + take(BN * 256);
    float* VMN  = ws + take(BN * 256);
    float* SSUM = ws + take(64 * 256);
    float* SSQ  = ws + take(64 * 256);
    float* WT1  = ws + take(384);
    float* WT2  = ws + take(8192);     // retained for layout stability (unused)
    float* WT3  = ws + take(16384);    // retained (unused)
    float* WT4  = ws + take(65536);    // retained (unused)
    float* FCT1 = ws + take(524288);
    float* FCT2 = ws + take(131072);
    float* X1   = ws + take(BN * 64);
    float* X2   = ws + take(BN * 64);
    float* X3   = ws + take(BN * 128);
    float* X4   = ws + take(BN * 256);
    float* PMAX = ws + take((size_t)Bb * 16 * 512);
    float* PSUM = ws + take((size_t)Bb * 16 * 512);
    (void)WT2; (void)WT3; (void)WT4;

    // head partial buffers alias DIST (dead after the last topk_kernel).
    float* HP1 = DIST;                       // 8*16*512 = 65536 floats
    float* HH  = DIST + 65536;               // 8*512 = 4096
    float* HP2 = DIST + 65536 + 4096;        // 8*4*256 = 8192

    // Weight transposes still needed: WT1 (layer-1 prep), FCT1/FCT2 (head).
    TransJobs tj;
    tj.in[0] = W1;    tj.out[0] = WT1;  tj.R[0] = 64;  tj.Cc[0] = 6;
    tj.in[1] = fc1_w; tj.out[1] = FCT1; tj.R[1] = 512; tj.Cc[1] = 1024;
    tj.in[2] = fc2_w; tj.out[2] = FCT2; tj.R[2] = 256; tj.Cc[2] = 512;
    transpose_all_kernel<<<dim3(2048, 3), 256, 0, stream>>>(tj);

    run_layer<3, 64>(points, W1, g1, b1, X1, DIST, XX, XP, IDX, Z1, Z2, VMX, VMN, SSUM, SSQ, WT1, PMAX, PSUM, 0, big, stream);
    run_layer<64, 64>(X1, W2, g2, b2, X2, DIST, XX, XP, IDX, Z1, Z2, VMX, VMN, SSUM, SSQ, WT1, PMAX, PSUM, 64, big, stream);
    run_layer<64, 128>(X2, W3, g3, b3, X3, DIST, XX, XP, IDX, Z1, Z2, VMX, VMN, SSUM, SSQ, WT1, PMAX, PSUM, 128, big, stream);
    run_layer<128, 256>(X3, W4, g4, b4, X4, DIST, XX, XP, IDX, Z1, Z2, VMX, VMN, SSUM, SSQ, WT1, PMAX, PSUM, 256, big, stream);

    head1_kernel<<<dim3(16, 8), 256, 0, stream>>>(PMAX, PSUM, FCT1, HP1);
    head2_kernel<<<Bb, 256, 0, stream>>>(HP1, fc1_b, ln1g, ln1b, HH);
    head3_kernel<<<dim3(4, 8), 256, 0, stream>>>(HH, FCT2, HP2);
    head4_kernel<<<Bb, 256, 0, stream>>>(HP2, fc2_b, ln2g, ln2b, (float*)d_out);
}

// Round 9
// 517.778 us; speedup vs baseline: 1.0876x; 1.0876x over previous
//
#include <hip/hip_runtime.h>
#include <cstdint>
#include <cstddef>

static constexpr int Bb = 8;
static constexpr int Nn = 2048;
static constexpr int Kn = 20;
static constexpr float EPSV = 1e-5f;

// ---------------------------------------------------------------- utilities

// weight transposes in one launch: out[c*R + r] = in[r*Cc + c]
struct TransJobs {
    const float* in[6];
    float* out[6];
    int R[6];
    int Cc[6];
};

__global__ void transpose_all_kernel(TransJobs tj) {
    int m = blockIdx.y;
    int i = blockIdx.x * 256 + threadIdx.x;
    int total = tj.R[m] * tj.Cc[m];
    if (i < total) {
        int r = i / tj.Cc[m], c = i % tj.Cc[m];
        tj.out[m][(size_t)c * tj.R[m] + r] = tj.in[m][i];
    }
}

using half8 = __attribute__((ext_vector_type(8))) _Float16;
using f32x16 = __attribute__((ext_vector_type(16))) float;

// ------------------- layer-1 prep (C=3 only): z-projection + packed xx + zero
// blocks [0,1024): Z1/Z2 projection for a 16-point tile
// blocks [1024,1088): xx[i] + packed (x,xx) float4
// blocks [1088,1216): zero the 32K-float SSUM+SSQ region

template<int C, int O>
__global__ void prep_kernel(const float* __restrict__ x, const float* __restrict__ wt,
                            float* __restrict__ z1, float* __restrict__ z2,
                            float* __restrict__ xx, float4* __restrict__ xp,
                            float* __restrict__ zp) {
    const int blk = blockIdx.x;
    const int tid = threadIdx.x;
    if (blk >= 1088) {
        zp[(blk - 1088) * 256 + tid] = 0.f;
        return;
    }
    if (blk >= 1024) {
        int i = (blk - 1024) * 256 + tid;
        const float* xr = x + (size_t)i * C;
        float s = 0.f;
        for (int c = 0; c < C; ++c) { float v = xr[c]; s += v * v; }
        xx[i] = s;
        if (C == 3) xp[i] = make_float4(xr[0], xr[1], xr[2], s);
        return;
    }
    // z projection (layer 1 path)
    constexpr int TP = 16;
    constexpr int G = 256 / O;
    constexpr int PP = TP / G;
    const int p0 = blk * TP;
    const int oo = tid % O;
    const int g = tid / O;
    __shared__ float xs[TP][(C < 4) ? 4 : C];
    for (int e = tid; e < TP * C; e += 256) {
        int p = e / C, c = e % C;
        xs[p][c] = x[(size_t)(p0 + p) * C + c];
    }
    __syncthreads();
    float a1[PP], a2[PP];
#pragma unroll
    for (int p = 0; p < PP; ++p) { a1[p] = 0.f; a2[p] = 0.f; }
    for (int c = 0; c < C; ++c) {
        float w1 = wt[(size_t)c * O + oo];
        float w2 = wt[(size_t)(C + c) * O + oo];
#pragma unroll
        for (int p = 0; p < PP; ++p) {
            float xv = xs[g * PP + p][c];
            a1[p] = fmaf(xv, w1, a1[p]);
            a2[p] = fmaf(xv, w2, a2[p]);
        }
    }
#pragma unroll
    for (int p = 0; p < PP; ++p) {
        size_t row = (size_t)(p0 + g * PP + p) * O + oo;
        z1[row] = a1[p];
        z2[row] = a2[p];
    }
}

// ------------------- layers 2-4 tiny prep: xx (exact old order) + stat-zero

template<int C>
__global__ void slim2_prep_kernel(const float* __restrict__ x,
                                  float* __restrict__ xx, float* __restrict__ zp) {
    const int blk = blockIdx.x;
    const int tid = threadIdx.x;
    if (blk < 64) {
        int i = blk * 256 + tid;
        const float* xr = x + (size_t)i * C;
        float s = 0.f;
        for (int c = 0; c < C; ++c) { float v = xr[c]; s += v * v; }
        xx[i] = s;
        return;
    }
    zp[(blk - 64) * 256 + tid] = 0.f;
}

// ------------------- z-projection on matrix cores (R16: gram-style clone)
// z1 = x @ W[:, :C]^T, z2 = x @ W[:, C:2C]^T via the verified 2-way fp16
// split (inner = hh + 2^-12*(h*l'+l*h')). Structure cloned from
// gram_dist_kernel: coalesced f32 panel loads -> inline h/l split ->
// rotated-slot LDS staging -> conflict-free ds_read_b128 fragments ->
// 2x2x2 MFMA.

template<int C, int O>
__global__ __launch_bounds__(256, 2)
void zmfma_kernel(const float* __restrict__ x, const float* __restrict__ w,
                  float* __restrict__ z1, float* __restrict__ z2) {
    static_assert(C % 32 == 0 && (2 * O) % 128 == 0 && O >= 64, "tiling");
    constexpr int CT = 32;
    const int i0 = blockIdx.x * 128;           // output rows (points)
    const int j0 = blockIdx.y * 128;           // output cols in [0, 2O)
    const int tid = threadIdx.x;
    const int lane = tid & 63;
    const int wv = tid >> 6;
    const int wr = wv >> 1, wc = wv & 1;

    __shared__ __align__(16) unsigned char smem[32768];
    _Float16* const AH = (_Float16*)smem;      // [4][128][8] halfs, 8 KB each
    _Float16* const AL = AH + 4096;
    _Float16* const BH = AH + 8192;
    _Float16* const BL = AH + 12288;

    int sga[4];
    const float* sgs[4];
#pragma unroll
    for (int q = 0; q < 4; ++q) {
        int g = tid + 256 * q;                 // q<2 -> A panel (x rows), q>=2 -> B panel (W rows)
        int pnt = (g >> 2) & 127;
        int cb8 = g & 3;
        sga[q] = cb8 * 128 + (pnt & ~7) + ((pnt + 2 * cb8) & 7);
        if (q < 2) {
            sgs[q] = x + (size_t)(i0 + pnt) * C + cb8 * 8;
        } else {
            int gcol = j0 + pnt;
            int s = (gcol >= O) ? 1 : 0;
            int o = gcol - s * O;
            sgs[q] = w + (size_t)o * (2 * C) + s * C + cb8 * 8;
        }
    }

    int fa[2][2], fb[2][2];
#pragma unroll
    for (int ks = 0; ks < 2; ++ks)
#pragma unroll
        for (int mi = 0; mi < 2; ++mi) {
            int t8 = ks * 2 + (lane >> 5);
            int pa = wr * 64 + mi * 32 + (lane & 31);
            int pb = wc * 64 + mi * 32 + (lane & 31);
            fa[ks][mi] = t8 * 128 + (pa & ~7) + ((pa + 2 * t8) & 7);
            fb[ks][mi] = t8 * 128 + (pb & ~7) + ((pb + 2 * t8) & 7);
        }

    f32x16 ahh[2][2] = {};   // SUM h*h'
    f32x16 axx[2][2] = {};   // SUM h*l' + l*h'   (carries the 4096 scale)

    for (int c0 = 0; c0 < C; c0 += CT) {
#pragma unroll
        for (int q = 0; q < 4; ++q) {
            const float4 f0 = *(const float4*)(sgs[q] + c0);
            const float4 f1 = *(const float4*)(sgs[q] + c0 + 4);
            float v[8] = {f0.x, f0.y, f0.z, f0.w, f1.x, f1.y, f1.z, f1.w};
            half8 hv, lv;
#pragma unroll
            for (int e = 0; e < 8; ++e) {
                _Float16 h = (_Float16)v[e];
                hv[e] = h;
                lv[e] = (_Float16)((v[e] - (float)h) * 4096.f);
            }
            _Float16* dh = (q < 2) ? AH : BH;
            _Float16* dl = (q < 2) ? AL : BL;
            *(half8*)(dh + sga[q] * 8) = hv;
            *(half8*)(dl + sga[q] * 8) = lv;
        }
        __syncthreads();
#pragma unroll
        for (int ks = 0; ks < 2; ++ks) {
            half8 ah[2], al[2], bh[2], bl[2];
#pragma unroll
            for (int mi = 0; mi < 2; ++mi) {
                ah[mi] = *(const half8*)(AH + fa[ks][mi] * 8);
                al[mi] = *(const half8*)(AL + fa[ks][mi] * 8);
                bh[mi] = *(const half8*)(BH + fb[ks][mi] * 8);
                bl[mi] = *(const half8*)(BL + fb[ks][mi] * 8);
            }
#pragma unroll
            for (int mi = 0; mi < 2; ++mi)
#pragma unroll
                for (int ni = 0; ni < 2; ++ni) {
                    ahh[mi][ni] = __builtin_amdgcn_mfma_f32_32x32x16_f16(ah[mi], bh[ni], ahh[mi][ni], 0, 0, 0);
                    axx[mi][ni] = __builtin_amdgcn_mfma_f32_32x32x16_f16(ah[mi], bl[ni], axx[mi][ni], 0, 0, 0);
                    axx[mi][ni] = __builtin_amdgcn_mfma_f32_32x32x16_f16(al[mi], bh[ni], axx[mi][ni], 0, 0, 0);
                }
        }
        __syncthreads();
    }

    // epilogue: z = hh + 2^-12 * cross; per-(wc,ni) wave-uniform z1/z2 select.
    // C/D layout: col = lane&31, row = (r&3) + 8*(r>>2) + 4*(lane>>5).
#pragma unroll
    for (int mi = 0; mi < 2; ++mi)
#pragma unroll
        for (int ni = 0; ni < 2; ++ni) {
            const int cb = wc * 64 + ni * 32;
            const int s = ((j0 + cb) >= O) ? 1 : 0;
            float* outp = s ? z2 : z1;
            const int o = j0 + cb - s * O + (lane & 31);
#pragma unroll
            for (int r = 0; r < 16; ++r) {
                int row = i0 + wr * 64 + mi * 32 + (r & 3) + 8 * (r >> 2) + 4 * (lane >> 5);
                outp[(size_t)row * O + o] = fmaf(axx[mi][ni][r], 2.44140625e-4f, ahh[mi][ni][r]);
            }
        }
}

// ------------------------------------------------ pairwise sq-dist (tiled gram)
// SYMMETRIC: only the 136 upper-triangular 128x128 block-pairs are computed.
// R18: gram is WRITE-BANDWIDTH-bound (131 MB store stream; practical
// one-direction ceiling ~3.15 TB/s per m13's 6.29 TB/s bidirectional copy).
// Every __syncthreads drains vmcnt(0), so any global store issued BEFORE a
// barrier serializes that block's store retirement at fair-share BW and gaps
// the store stream. Epilogue order for off-diagonal blocks is therefore:
//   (1) mirror tile -> T2 (LDS only)  (2) ONE barrier (VMEM queue empty ->
//   drain is free)  (3) main-tile stores + mirror copy-out in one burst,
//   retired overlapped with other blocks (end-of-kernel drain only).
// R10: matrix-core inner products via 2-way fp16 split.
// R11 (rule #20): accumulator subscripts must be compile-time — runtime
// indexing sent f32x16 accs to SCRATCH (1.27 GB HBM traffic, 276 us).

template<int C>
__global__ __launch_bounds__(256, 2)
void gram_dist_kernel(const float* __restrict__ x, const float* __restrict__ xx,
                      float* __restrict__ dist, int b0, size_t dstride) {
    static_assert(C % 32 == 0, "CT=32 tiling");
    constexpr int CT = 32;
    const int b = b0 + blockIdx.z;
    // decode upper-tri pair index -> (rblk, cblk), rblk <= cblk, 16x16 tiles
    int p = blockIdx.x, rblk = 0;
    while (p >= 16 - rblk) { p -= 16 - rblk; ++rblk; }
    const int cblk = rblk + p;
    const int i0 = rblk * 128, j0 = cblk * 128;
    const int tid = threadIdx.x;
    const int lane = tid & 63;
    const int wv = tid >> 6;
    const int wr = wv >> 1, wc = wv & 1;   // wave quadrant: rows wr*64.., cols wc*64..

    __shared__ __align__(16) unsigned char smem[67584];   // max(staging 32KB, T2 128*132*4)
    _Float16* const AH = (_Float16*)smem;          // [4][128][8] halfs, 8 KB
    _Float16* const AL = AH + 4096;
    _Float16* const BH = AH + 8192;
    _Float16* const BL = AH + 12288;
    float (*T2)[132] = (float (*)[132])smem;       // full mirror buffer, post-loop alias

    const float* xb = x + (size_t)b * Nn * C;
    int sga[4];
    const float* sgs[4];
#pragma unroll
    for (int q = 0; q < 4; ++q) {
        int g = tid + 256 * q;                 // q<2 -> A panel (i0), q>=2 -> B panel (j0)
        int pnt = (g >> 2) & 127;
        int cb8 = g & 3;
        sga[q] = cb8 * 128 + (pnt & ~7) + ((pnt + 2 * cb8) & 7);
        sgs[q] = xb + (size_t)(((q < 2) ? i0 : j0) + pnt) * C + cb8 * 8;
    }

    int fa[2][2], fb[2][2];
#pragma unroll
    for (int ks = 0; ks < 2; ++ks)
#pragma unroll
        for (int mi = 0; mi < 2; ++mi) {
            int t8 = ks * 2 + (lane >> 5);
            int pa = wr * 64 + mi * 32 + (lane & 31);
            int pb = wc * 64 + mi * 32 + (lane & 31);
            fa[ks][mi] = t8 * 128 + (pa & ~7) + ((pa + 2 * t8) & 7);
            fb[ks][mi] = t8 * 128 + (pb & ~7) + ((pb + 2 * t8) & 7);
        }

    f32x16 ahh[2][2] = {};   // SUM h*h'
    f32x16 axx[2][2] = {};   // SUM h*l' + l*h'   (carries the 4096 scale)

    for (int c0 = 0; c0 < C; c0 += CT) {
#pragma unroll
        for (int q = 0; q < 4; ++q) {
            const float4 f0 = *(const float4*)(sgs[q] + c0);
            const float4 f1 = *(const float4*)(sgs[q] + c0 + 4);
            float v[8] = {f0.x, f0.y, f0.z, f0.w, f1.x, f1.y, f1.z, f1.w};
            half8 hv, lv;
#pragma unroll
            for (int e = 0; e < 8; ++e) {
                _Float16 h = (_Float16)v[e];
                hv[e] = h;
                lv[e] = (_Float16)((v[e] - (float)h) * 4096.f);
            }
            _Float16* dh = (q < 2) ? AH : BH;
            _Float16* dl = (q < 2) ? AL : BL;
            *(half8*)(dh + sga[q] * 8) = hv;
            *(half8*)(dl + sga[q] * 8) = lv;
        }
        __syncthreads();
#pragma unroll
        for (int ks = 0; ks < 2; ++ks) {
            half8 ah[2], al[2], bh[2], bl[2];
#pragma unroll
            for (int mi = 0; mi < 2; ++mi) {
                ah[mi] = *(const half8*)(AH + fa[ks][mi] * 8);
                al[mi] = *(const half8*)(AL + fa[ks][mi] * 8);
                bh[mi] = *(const half8*)(BH + fb[ks][mi] * 8);
                bl[mi] = *(const half8*)(BL + fb[ks][mi] * 8);
            }
#pragma unroll
            for (int mi = 0; mi < 2; ++mi)
#pragma unroll
                for (int ni = 0; ni < 2; ++ni) {
                    ahh[mi][ni] = __builtin_amdgcn_mfma_f32_32x32x16_f16(ah[mi], bh[ni], ahh[mi][ni], 0, 0, 0);
                    axx[mi][ni] = __builtin_amdgcn_mfma_f32_32x32x16_f16(ah[mi], bl[ni], axx[mi][ni], 0, 0, 0);
                    axx[mi][ni] = __builtin_amdgcn_mfma_f32_32x32x16_f16(al[mi], bh[ni], axx[mi][ni], 0, 0, 0);
                }
        }
        __syncthreads();
    }

    // epilogue: dist = xx_i + xx_j - 2*(hh + 2^-12 * cross)
    const float* xxb = xx + (size_t)b * Nn;
    float xi[2][16];
#pragma unroll
    for (int mi = 0; mi < 2; ++mi)
#pragma unroll
        for (int g = 0; g < 4; ++g) {
            float4 t4 = *(const float4*)(xxb + i0 + wr * 64 + mi * 32 + 4 * (lane >> 5) + 8 * g);
            xi[mi][g * 4 + 0] = t4.x; xi[mi][g * 4 + 1] = t4.y;
            xi[mi][g * 4 + 2] = t4.z; xi[mi][g * 4 + 3] = t4.w;
        }
    float xj[2];
#pragma unroll
    for (int ni = 0; ni < 2; ++ni) xj[ni] = xxb[j0 + wc * 64 + ni * 32 + (lane & 31)];

    float* db = dist + (size_t)blockIdx.z * dstride;

    if (cblk == rblk) {
        // diagonal: main tile only, store directly.
#pragma unroll
        for (int mi = 0; mi < 2; ++mi)
#pragma unroll
            for (int ni = 0; ni < 2; ++ni) {
                const int col = j0 + wc * 64 + ni * 32 + (lane & 31);
#pragma unroll
                for (int r = 0; r < 16; ++r) {
                    int row = i0 + wr * 64 + mi * 32 + (r & 3) + 8 * (r >> 2) + 4 * (lane >> 5);
                    float inner = fmaf(axx[mi][ni][r], 2.44140625e-4f, ahh[mi][ni][r]);
                    db[(size_t)row * Nn + col] = xi[mi][r] + xj[ni] - 2.f * inner;
                }
            }
    } else {
        // off-diagonal: (1) mirror -> T2 (LDS only); (2) one barrier with an
        // empty VMEM queue; (3) all global stores in one uninterrupted burst.
#pragma unroll
        for (int mi = 0; mi < 2; ++mi)
#pragma unroll
            for (int ni = 0; ni < 2; ++ni) {
                const int mrow = wc * 64 + ni * 32 + (lane & 31);   // mirror row (orig col)
#pragma unroll
                for (int r = 0; r < 16; ++r) {
                    int mcol = wr * 64 + mi * 32 + (r & 3) + 8 * (r >> 2) + 4 * (lane >> 5);
                    float inner = fmaf(axx[mi][ni][r], 2.44140625e-4f, ahh[mi][ni][r]);
                    T2[mrow][mcol] = xi[mi][r] + xj[ni] - 2.f * inner;
                }
            }
        __syncthreads();
        // main tile stores
#pragma unroll
        for (int mi = 0; mi < 2; ++mi)
#pragma unroll
            for (int ni = 0; ni < 2; ++ni) {
                const int col = j0 + wc * 64 + ni * 32 + (lane & 31);
#pragma unroll
                for (int r = 0; r < 16; ++r) {
                    int row = i0 + wr * 64 + mi * 32 + (r & 3) + 8 * (r >> 2) + 4 * (lane >> 5);
                    float inner = fmaf(axx[mi][ni][r], 2.44140625e-4f, ahh[mi][ni][r]);
                    db[(size_t)row * Nn + col] = xi[mi][r] + xj[ni] - 2.f * inner;
                }
            }
        // mirror copy-out (coalesced)
        const int rr = tid >> 3;            // 0..31 row within 32-row group
        const int c4 = (tid & 7) * 4;       // col base (float4 granularity)
#pragma unroll
        for (int m = 0; m < 4; ++m) {
            const int row = m * 32 + rr;
            float* orow = db + (size_t)(j0 + row) * Nn + i0;
#pragma unroll
            for (int s = 0; s < 4; ++s)
                *(float4*)(orow + c4 + s * 32) = *(const float4*)&T2[row][c4 + s * 32];
        }
    }
}

// ------------------------------------------------------- top-k (k=20 smallest)
// R14: PACKED-KEY selection. In-lane candidate ordinal m (5 bits) is packed
// into the 5 low mantissa bits: key = (bits(v) & ~31) | m. In-lane keys are
// distinct -> strict-< ladder exact; winner decode free (m from key bits,
// lane from ballot); no tie-butterfly; rebuild filter = single compare.
// Ranking perturbation 2^-19 rel ~ same class as fp16-split dist error.

template<int CTRL>
__device__ __forceinline__ float dpp_min_step(float v) {
    int x = __float_as_int(v);
    int y = __builtin_amdgcn_update_dpp(x, x, CTRL, 0xf, 0xf, false);
    return fminf(v, __int_as_float(y));
}

// full-wave (64-lane) min; returns the min broadcast to all lanes (SGPR).
__device__ __forceinline__ float wave_min64(float v) {
    v = dpp_min_step<0x111>(v);   // row_shr:1
    v = dpp_min_step<0x112>(v);   // row_shr:2
    v = dpp_min_step<0x114>(v);   // row_shr:4
    v = dpp_min_step<0x118>(v);   // row_shr:8
    v = dpp_min_step<0x142>(v);   // row_bcast:15
    v = dpp_min_step<0x143>(v);   // row_bcast:31
    return __int_as_float(__builtin_amdgcn_readlane(__float_as_int(v), 63));
}

__device__ __forceinline__ float pack_key(float v, int m) {
    return __int_as_float((__float_as_int(v) & ~31) | m);
}

#define TOP4_INS(v)                                                               \
    {                                                                             \
        bool l3 = (v) < tv3;                                                      \
        if (l3) {                                                                 \
            bool l2 = (v) < tv2;                                                  \
            bool l1 = (v) < tv1;                                                  \
            bool l0 = (v) < tv0;                                                  \
            tv3 = l2 ? tv2 : (v);                                                 \
            tv2 = l2 ? (l1 ? tv1 : (v)) : tv2;                                    \
            tv1 = l1 ? (l0 ? tv0 : (v)) : tv1;                                    \
            tv0 = l0 ? (v) : tv0;                                                 \
        }                                                                         \
    }

__device__ __forceinline__ void top4_build(const float4* __restrict__ dr4, int lane,
                                           float lvk,
                                           float& tv0, float& tv1, float& tv2, float& tv3) {
    tv0 = tv1 = tv2 = tv3 = 3e38f;
#pragma unroll
    for (int q = 0; q < 8; ++q) {
        float4 f = dr4[q * 64 + lane];
        float vv[4] = {f.x, f.y, f.z, f.w};
#pragma unroll
        for (int c = 0; c < 4; ++c) {
            float vk = pack_key(vv[c], q * 4 + c);
            if (vk > lvk) TOP4_INS(vk)
        }
    }
}

#define TOPK_ROUNDS(REBUILD, DECODE)                                              \
    int myj = 0;                                                                  \
    for (int t = 0; t < Kn; ++t) {                                                \
        float bv = wave_min64(tv0);                                               \
        unsigned long long tied = __ballot(tv0 == bv);                            \
        int wl = (int)(__ffsll((long long)tied) - 1);                             \
        int bm = __float_as_int(bv) & 31;                                         \
        int bj = (DECODE);                                                        \
        if (lane == t) myj = bj;                                                  \
        if (tv0 == bv && lane == wl) {                                            \
            tv0 = tv1; tv1 = tv2; tv2 = tv3; tv3 = 3e38f;                         \
            if (tv0 == 3e38f) { REBUILD; }                                        \
        }                                                                         \
    }                                                                             \
    if (lane < Kn) orow[lane] = myj;

__global__ void topk_kernel(const float* __restrict__ dist, int* __restrict__ idxo,
                            int b0, size_t dstride, int rows_per_batch_only) {
    const int w = threadIdx.x >> 6;
    const int lane = threadIdx.x & 63;
    const int lin = blockIdx.x * 4 + w;
    int bz, i;
    if (rows_per_batch_only) { bz = 0; i = lin; }
    else { bz = lin >> 11; i = lin & (Nn - 1); }
    const int b = b0 + bz;
    const float4* dr4 = (const float4*)(dist + (size_t)bz * dstride + (size_t)i * Nn);

    float tv0, tv1, tv2, tv3;
    top4_build(dr4, lane, -3e38f, tv0, tv1, tv2, tv3);

    int* orow = idxo + ((size_t)b * Nn + i) * Kn;
    // j = (q*64+lane)*4 + c, m = q*4+c  ->  j = (m>>2)*256 + lane*4 + (m&3)
    TOPK_ROUNDS(top4_build(dr4, lane, bv, tv0, tv1, tv2, tv3),
                (bm >> 2) * 256 + wl * 4 + (bm & 3))
}

// -------- layer-1 fused top-k: dist computed inline from packed (x,xx) float4.

__device__ __forceinline__ void top4_build_c3(const float4* __restrict__ xpb,
                                              float xi0, float xi1, float xi2, float xxi,
                                              int lane, float lvk,
                                              float& tv0, float& tv1, float& tv2, float& tv3) {
    tv0 = tv1 = tv2 = tv3 = 3e38f;
#pragma unroll
    for (int m = 0; m < 32; ++m) {
        float4 f = xpb[m * 64 + lane];
        float acc = 0.f;
        acc = fmaf(xi0, f.x, acc);
        acc = fmaf(xi1, f.y, acc);
        acc = fmaf(xi2, f.z, acc);
        float v = xxi + f.w - 2.f * acc;
        float vk = pack_key(v, m);
        if (vk > lvk) TOP4_INS(vk)
    }
}

__global__ void topk_c3_kernel(const float4* __restrict__ xp, int* __restrict__ idxo,
                               int b0, int rows_per_batch_only) {
    const int w = threadIdx.x >> 6;
    const int lane = threadIdx.x & 63;
    const int lin = blockIdx.x * 4 + w;
    int bz, i;
    if (rows_per_batch_only) { bz = 0; i = lin; }
    else { bz = lin >> 11; i = lin & (Nn - 1); }
    const int b = b0 + bz;
    const float4* xpb = xp + (size_t)b * Nn;
    const float4 fi = xpb[i];
    const float xi0 = fi.x, xi1 = fi.y, xi2 = fi.z, xxi = fi.w;

    float tv0, tv1, tv2, tv3;
    top4_build_c3(xpb, xi0, xi1, xi2, xxi, lane, -3e38f, tv0, tv1, tv2, tv3);

    int* orow = idxo + ((size_t)b * Nn + i) * Kn;
    // j = m*64 + lane
    TOPK_ROUNDS(top4_build_c3(xpb, xi0, xi1, xi2, xxi, lane, bv, tv0, tv1, tv2, tv3),
                bm * 64 + wl)
}

// -------------------- gather edges, max/min over k + BN partial sums

template<int O>
__global__ void edge_stats_kernel(const float* __restrict__ z1, const float* __restrict__ z2,
                                  const int* __restrict__ idx,
                                  float* __restrict__ vmax, float* __restrict__ vmin,
                                  float* __restrict__ ssum, float* __restrict__ ssq) {
    constexpr int TPP = O / 4;           // threads per point
    constexpr int PPB = 256 / TPP;       // points per block
    const int p0 = blockIdx.x * PPB;
    const int tid = threadIdx.x;
    const int q = tid % TPP;
    const int p = tid / TPP;
    const int oo = q * 4;
    __shared__ int jl[PPB][Kn];
    for (int e = tid; e < PPB * Kn; e += 256)
        jl[e / Kn][e % Kn] = idx[(size_t)(p0 + e / Kn) * Kn + (e % Kn)];
    __syncthreads();
    const int bi = p0 + p;
    const int b = bi >> 11;
    const float4 zi1 = *(const float4*)(z1 + (size_t)bi * O + oo);
    const float4 zi2 = *(const float4*)(z2 + (size_t)bi * O + oo);
    float ax = zi2.x - zi1.x, ay = zi2.y - zi1.y, az = zi2.z - zi1.z, aw = zi2.w - zi1.w;
    float mxx = -3e38f, mxy = -3e38f, mxz = -3e38f, mxw = -3e38f;
    float mnx = 3e38f, mny = 3e38f, mnz = 3e38f, mnw = 3e38f;
    float sx = 0.f, sy = 0.f, sz = 0.f, sw = 0.f;
    float qx = 0.f, qy = 0.f, qz = 0.f, qw = 0.f;
    const float* zbase = z1 + ((size_t)b * Nn) * O + oo;
#pragma unroll
    for (int kk = 0; kk < Kn; ++kk) {
        int j = jl[p][kk];
        float4 v = *(const float4*)(zbase + (size_t)j * O);
        v.x += ax; v.y += ay; v.z += az; v.w += aw;
        mxx = fmaxf(mxx, v.x); mxy = fmaxf(mxy, v.y); mxz = fmaxf(mxz, v.z); mxw = fmaxf(mxw, v.w);
        mnx = fminf(mnx, v.x); mny = fminf(mny, v.y); mnz = fminf(mnz, v.z); mnw = fminf(mnw, v.w);
        sx += v.x; sy += v.y; sz += v.z; sw += v.w;
        qx = fmaf(v.x, v.x, qx); qy = fmaf(v.y, v.y, qy);
        qz = fmaf(v.z, v.z, qz); qw = fmaf(v.w, v.w, qw);
    }
    float4 mx4 = make_float4(mxx, mxy, mxz, mxw);
    float4 mn4 = make_float4(mnx, mny, mnz, mnw);
    *(float4*)(vmax + (size_t)bi * O + oo) = mx4;
    *(float4*)(vmin + (size_t)bi * O + oo) = mn4;
    __shared__ float4 ssm[256], sqq[256];
    ssm[tid] = make_float4(sx, sy, sz, sw);
    sqq[tid] = make_float4(qx, qy, qz, qw);
    __syncthreads();
    if (p == 0) {
#pragma unroll 4
        for (int pp = 1; pp < PPB; ++pp) {
            float4 s4 = ssm[pp * TPP + q];
            float4 q4 = sqq[pp * TPP + q];
            sx += s4.x; sy += s4.y; sz += s4.z; sw += s4.w;
            qx += q4.x; qy += q4.y; qz += q4.z; qw += q4.w;
        }
        int slot = blockIdx.x & 63;
        atomicAdd(&ssum[slot * O + oo + 0], sx);
        atomicAdd(&ssum[slot * O + oo + 1], sy);
        atomicAdd(&ssum[slot * O + oo + 2], sz);
        atomicAdd(&ssum[slot * O + oo + 3], sw);
        atomicAdd(&ssq[slot * O + oo + 0], qx);
        atomicAdd(&ssq[slot * O + oo + 1], qy);
        atomicAdd(&ssq[slot * O + oo + 2], qz);
        atomicAdd(&ssq[slot * O + oo + 3], qw);
    }
}

// ---------------- BN finalize (in-block) + apply + relu + pooling partials

template<int O>
__global__ void apply_pool_kernel(const float* __restrict__ vmax, const float* __restrict__ vmin,
                                  const float* __restrict__ ssum, const float* __restrict__ ssq,
                                  const float* __restrict__ gamma, const float* __restrict__ beta,
                                  float* __restrict__ xout,
                                  float* __restrict__ pmax, float* __restrict__ psum, int obase) {
    constexpr int TPP = O / 4;
    constexpr int PP2 = 256 / TPP;      // points concurrent
    constexpr int S = 128 / PP2;        // iterations
    const int chunk = blockIdx.x;
    const int b = blockIdx.y;
    const int tid = threadIdx.x;
    const int q = tid % TPP;
    const int g = tid / TPP;
    const int oo = q * 4;
    __shared__ __align__(16) float lsc[O], lsh[O];
    for (int o = tid; o < O; o += 256) {
        float s = 0.f, qq = 0.f;
        for (int sl = 0; sl < 64; ++sl) { s += ssum[sl * O + o]; qq += ssq[sl * O + o]; }
        const float cnt = (float)Bb * (float)Nn * (float)Kn;
        float mu = s / cnt;
        float var = qq / cnt - mu * mu;
        float sc_ = gamma[o] / sqrtf(var + EPSV);
        lsc[o] = sc_;
        lsh[o] = beta[o] - mu * sc_;
    }
    __syncthreads();
    const float4 sc = *(const float4*)(lsc + oo);
    const float4 sh = *(const float4*)(lsh + oo);
    float pmx = -3e38f, pmy = -3e38f, pmz = -3e38f, pmw = -3e38f;
    float psx = 0.f, psy = 0.f, psz = 0.f, psw = 0.f;
    const int n0 = chunk * 128;
    for (int s = 0; s < S; ++s) {
        int n = n0 + g + s * PP2;
        size_t ix = ((size_t)b * Nn + n) * O + oo;
        float4 vx = *(const float4*)(vmax + ix);
        float4 vn = *(const float4*)(vmin + ix);
        float4 r;
        r.x = fmaxf(fmaf(sc.x >= 0.f ? vx.x : vn.x, sc.x, sh.x), 0.f);
        r.y = fmaxf(fmaf(sc.y >= 0.f ? vx.y : vn.y, sc.y, sh.y), 0.f);
        r.z = fmaxf(fmaf(sc.z >= 0.f ? vx.z : vn.z, sc.z, sh.z), 0.f);
        r.w = fmaxf(fmaf(sc.w >= 0.f ? vx.w : vn.w, sc.w, sh.w), 0.f);
        *(float4*)(xout + ix) = r;
        pmx = fmaxf(pmx, r.x); pmy = fmaxf(pmy, r.y);
        pmz = fmaxf(pmz, r.z); pmw = fmaxf(pmw, r.w);
        psx += r.x; psy += r.y; psz += r.z; psw += r.w;
    }
    __shared__ float4 sm[256], ss2[256];
    sm[tid] = make_float4(pmx, pmy, pmz, pmw);
    ss2[tid] = make_float4(psx, psy, psz, psw);
    __syncthreads();
    if (g == 0) {
#pragma unroll 4
        for (int gg = 1; gg < PP2; ++gg) {
            float4 m4 = sm[gg * TPP + q];
            float4 s4 = ss2[gg * TPP + q];
            pmx = fmaxf(pmx, m4.x); pmy = fmaxf(pmy, m4.y);
            pmz = fmaxf(pmz, m4.z); pmw = fmaxf(pmw, m4.w);
            psx += s4.x; psy += s4.y; psz += s4.z; psw += s4.w;
        }
        size_t pb = ((size_t)b * 16 + chunk) * 512 + obase + oo;
        *(float4*)(pmax + pb) = make_float4(pmx, pmy, pmz, pmw);
        *(float4*)(psum + pb) = make_float4(psx, psy, psz, psw);
    }
}

// ------------------------------------------- MLP head, K-parallel (R12)

__global__ void head1_kernel(const float* __restrict__ pmax, const float* __restrict__ psum,
                             const float* __restrict__ fct1, float* __restrict__ hp1) {
    const int ks = blockIdx.x;          // 0..15 -> input channels [ks*64, ks*64+64)
    const int b = blockIdx.y;
    const int tid = threadIdx.x;
    __shared__ float gxs[64];
    if (tid < 64) {
        int c = ks * 64 + tid;
        if (c < 512) {
            float mx = -3e38f;
            for (int ch = 0; ch < 16; ++ch)
                mx = fmaxf(mx, pmax[((size_t)b * 16 + ch) * 512 + c]);
            gxs[tid] = mx;
        } else {
            int e = c - 512;
            float s = 0.f;
            for (int ch = 0; ch < 16; ++ch)
                s += psum[((size_t)b * 16 + ch) * 512 + e];
            gxs[tid] = s * (1.f / (float)Nn);
        }
    }
    __syncthreads();
    float h0 = 0.f, h1 = 0.f;
    const float* w = fct1 + (size_t)(ks * 64) * 512;
    for (int c = 0; c < 64; ++c) {
        float gc = gxs[c];
        h0 = fmaf(gc, w[(size_t)c * 512 + tid], h0);
        h1 = fmaf(gc, w[(size_t)c * 512 + tid + 256], h1);
    }
    hp1[((size_t)b * 16 + ks) * 512 + tid] = h0;
    hp1[((size_t)b * 16 + ks) * 512 + tid + 256] = h1;
}

__global__ void head2_kernel(const float* __restrict__ hp1, const float* __restrict__ fc1b,
                             const float* __restrict__ ln1g, const float* __restrict__ ln1b,
                             float* __restrict__ hh) {
    const int b = blockIdx.x;
    const int tid = threadIdx.x;
    __shared__ float red[256];
    float h0 = fc1b[tid], h1 = fc1b[tid + 256];
    for (int ks = 0; ks < 16; ++ks) {
        h0 += hp1[((size_t)b * 16 + ks) * 512 + tid];
        h1 += hp1[((size_t)b * 16 + ks) * 512 + tid + 256];
    }
    red[tid] = h0 + h1;
    __syncthreads();
    for (int st = 128; st > 0; st >>= 1) { if (tid < st) red[tid] += red[tid + st]; __syncthreads(); }
    float mu = red[0] * (1.f / 512.f);
    __syncthreads();
    float d0 = h0 - mu, d1 = h1 - mu;
    red[tid] = d0 * d0 + d1 * d1;
    __syncthreads();
    for (int st = 128; st > 0; st >>= 1) { if (tid < st) red[tid] += red[tid + st]; __syncthreads(); }
    float rs = 1.f / sqrtf(red[0] * (1.f / 512.f) + EPSV);
    hh[(size_t)b * 512 + tid]       = fmaxf(d0 * rs * ln1g[tid] + ln1b[tid], 0.f);
    hh[(size_t)b * 512 + tid + 256] = fmaxf(d1 * rs * ln1g[tid + 256] + ln1b[tid + 256], 0.f);
}

__global__ void head3_kernel(const float* __restrict__ hh, const float* __restrict__ fct2,
                             float* __restrict__ hp2) {
    const int ks = blockIdx.x;          // 0..3 -> hh channels [ks*128, ks*128+128)
    const int b = blockIdx.y;
    const int tid = threadIdx.x;
    __shared__ float hs[128];
    if (tid < 128) hs[tid] = hh[(size_t)b * 512 + ks * 128 + tid];
    __syncthreads();
    float z = 0.f;
    const float* w = fct2 + (size_t)(ks * 128) * 256;
    for (int c = 0; c < 128; ++c)
        z = fmaf(hs[c], w[(size_t)c * 256 + tid], z);
    hp2[((size_t)b * 4 + ks) * 256 + tid] = z;
}

__global__ void head4_kernel(const float* __restrict__ hp2, const float* __restrict__ fc2b,
                             const float* __restrict__ ln2g, const float* __restrict__ ln2b,
                             float* __restrict__ out) {
    const int b = blockIdx.x;
    const int tid = threadIdx.x;
    __shared__ float red[256];
    float z = fc2b[tid];
    for (int ks = 0; ks < 4; ++ks) z += hp2[((size_t)b * 4 + ks) * 256 + tid];
    red[tid] = z;
    __syncthreads();
    for (int st = 128; st > 0; st >>= 1) { if (tid < st) red[tid] += red[tid + st]; __syncthreads(); }
    float mu2 = red[0] * (1.f / 256.f);
    __syncthreads();
    float dz = z - mu2;
    red[tid] = dz * dz;
    __syncthreads();
    for (int st = 128; st > 0; st >>= 1) { if (tid < st) red[tid] += red[tid + st]; __syncthreads(); }
    float rs2 = 1.f / sqrtf(red[0] * (1.f / 256.f) + EPSV);
    out[b * 256 + tid] = dz * rs2 * ln2g[tid] + ln2b[tid];
}

// --------------------------------------------------------------- layer driver

template<int C, int O>
static void run_layer(const float* x, const float* W, const float* gamma, const float* beta,
                      float* xout, float* DIST, float* XX, float4* XP, int* IDX,
                      float* Z1, float* Z2,
                      float* VMX, float* VMN, float* SSUM, float* SSQ,
                      const float* WT, float* PMAX, float* PSUM, int obase, bool big,
                      hipStream_t stream) {
    if constexpr (C == 3) {
        prep_kernel<C, O><<<1216, 256, 0, stream>>>(x, WT, Z1, Z2, XX, XP, SSUM);
        // layer 1: packed (x,xx) is L1-resident -> fused inline-dist top-k.
        if (big) {
            topk_c3_kernel<<<Bb * Nn / 4, 256, 0, stream>>>(XP, IDX, 0, 0);
        } else {
            for (int b = 0; b < Bb; ++b)
                topk_c3_kernel<<<Nn / 4, 256, 0, stream>>>(XP, IDX, b, 1);
        }
    } else {
        // R16: tiny prep (xx + stat-zero) + gram-style MFMA z-projection.
        slim2_prep_kernel<C><<<192, 256, 0, stream>>>(x, XX, SSUM);
        zmfma_kernel<C, O><<<dim3(Bb * Nn / 128, 2 * O / 128), 256, 0, stream>>>(x, W, Z1, Z2);
        if (big) {
            gram_dist_kernel<C><<<dim3(136, 1, Bb), 256, 0, stream>>>(x, XX, DIST, 0, (size_t)Nn * Nn);
            topk_kernel<<<Bb * Nn / 4, 256, 0, stream>>>(DIST, IDX, 0, (size_t)Nn * Nn, 0);
        } else {
            for (int b = 0; b < Bb; ++b) {
                gram_dist_kernel<C><<<dim3(136, 1, 1), 256, 0, stream>>>(x, XX, DIST, b, 0);
                topk_kernel<<<Nn / 4, 256, 0, stream>>>(DIST, IDX, b, 0, 1);
            }
        }
    }
    edge_stats_kernel<O><<<Bb * Nn / (1024 / O), 256, 0, stream>>>(Z1, Z2, IDX, VMX, VMN, SSUM, SSQ);
    apply_pool_kernel<O><<<dim3(16, 8), 256, 0, stream>>>(VMX, VMN, SSUM, SSQ, gamma, beta,
                                                          xout, PMAX, PSUM, obase);
}

extern "C" void kernel_launch(void* const* d_in, const int* in_sizes, int n_in,
                              void* d_out, int out_size, void* d_ws, size_t ws_size,
                              hipStream_t stream) {
    const float* points = (const float*)d_in[0];
    const float* W1 = (const float*)d_in[1];
    const float* g1 = (const float*)d_in[2];
    const float* b1 = (const float*)d_in[3];
    const float* W2 = (const float*)d_in[4];
    const float* g2 = (const float*)d_in[5];
    const float* b2 = (const float*)d_in[6];
    const float* W3 = (const float*)d_in[7];
    const float* g3 = (const float*)d_in[8];
    const float* b3 = (const float*)d_in[9];
    const float* W4 = (const float*)d_in[10];
    const float* g4 = (const float*)d_in[11];
    const float* b4 = (const float*)d_in[12];
    const float* fc1_w = (const float*)d_in[13];
    const float* fc1_b = (const float*)d_in[14];
    const float* ln1g = (const float*)d_in[15];
    const float* ln1b = (const float*)d_in[16];
    const float* fc2_w = (const float*)d_in[17];
    const float* fc2_b = (const float*)d_in[18];
    const float* ln2g = (const float*)d_in[19];
    const float* ln2b = (const float*)d_in[20];

    float* ws = (float*)d_ws;
    const size_t BN = (size_t)Bb * Nn;
    const bool big = ws_size >= (size_t)59826688 * 4;

    size_t off = 0;
    auto take = [&](size_t n) { size_t o = off; off += n; return o; };
    float* DIST = ws + take(big ? (size_t)Bb * Nn * Nn : (size_t)Nn * Nn);
    float* XX   = ws + take(BN);
    float4* XP  = (float4*)(ws + take(BN * 4));
    int*   IDX  = (int*)(ws + take(BN * Kn));
    float* Z1   = ws + take(BN * 256);
    float* Z2   = ws + take(BN * 256);
    float* VMX  = ws + take(BN * 256);
    float* VMN  = ws + take(BN * 256);
    float* SSUM = ws + take(64 * 256);
    float* SSQ  = ws + take(64 * 256);
    float* WT1  = ws + take(384);
    float* WT2  = ws + take(8192);     // retained for layout stability (unused)
    float* WT3  = ws + take(16384);    // retained (unused)
    float* WT4  = ws + take(65536);    // retained (unused)
    float* FCT1 = ws + take(524288);
    float* FCT2 = ws + take(131072);
    float* X1   = ws + take(BN * 64);
    float* X2   = ws + take(BN * 64);
    float* X3   = ws + take(BN * 128);
    float* X4   = ws + take(BN * 256);
    float* PMAX = ws + take((size_t)Bb * 16 * 512);
    float* PSUM = ws + take((size_t)Bb * 16 * 512);
    (void)WT2; (void)WT3; (void)WT4;

    // head partial buffers alias DIST (dead after the last topk_kernel).
    float* HP1 = DIST;                       // 8*16*512 = 65536 floats
    float* HH  = DIST + 65536;               // 8*512 = 4096
    float* HP2 = DIST + 65536 + 4096;        // 8*4*256 = 8192

    // Weight transposes still needed: WT1 (layer-1 prep), FCT1/FCT2 (head).
    TransJobs tj;
    tj.in[0] = W1;    tj.out[0] = WT1;  tj.R[0] = 64;  tj.Cc[0] = 6;
    tj.in[1] = fc1_w; tj.out[1] = FCT1; tj.R[1] = 512; tj.Cc[1] = 1024;
    tj.in[2] = fc2_w; tj.out[2] = FCT2; tj.R[2] = 256; tj.Cc[2] = 512;
    transpose_all_kernel<<<dim3(2048, 3), 256, 0, stream>>>(tj);

    run_layer<3, 64>(points, W1, g1, b1, X1, DIST, XX, XP, IDX, Z1, Z2, VMX, VMN, SSUM, SSQ, WT1, PMAX, PSUM, 0, big, stream);
    run_layer<64, 64>(X1, W2, g2, b2, X2, DIST, XX, XP, IDX, Z1, Z2, VMX, VMN, SSUM, SSQ, WT1, PMAX, PSUM, 64, big, stream);
    run_layer<64, 128>(X2, W3, g3, b3, X3, DIST, XX, XP, IDX, Z1, Z2, VMX, VMN, SSUM, SSQ, WT1, PMAX, PSUM, 128, big, stream);
    run_layer<128, 256>(X3, W4, g4, b4, X4, DIST, XX, XP, IDX, Z1, Z2, VMX, VMN, SSUM, SSQ, WT1, PMAX, PSUM, 256, big, stream);

    head1_kernel<<<dim3(16, 8), 256, 0, stream>>>(PMAX, PSUM, FCT1, HP1);
    head2_kernel<<<Bb, 256, 0, stream>>>(HP1, fc1_b, ln1g, ln1b, HH);
    head3_kernel<<<dim3(4, 8), 256, 0, stream>>>(HH, FCT2, HP2);
    head4_kernel<<<Bb, 256, 0, stream>>>(HP2, fc2_b, ln2g, ln2b, (float*)d_out);
}